// Round 1
// baseline (1388.651 us; speedup 1.0000x reference)
//
#include <hip/hip_runtime.h>
#include <math.h>

#define D_MODEL 1024
#define NUM_HEADS 16
#define DK 64
#define BATCH 2
#define SEQ 2048

// ---------------------------------------------------------------------------
// GEMM: C = A @ W^T + bias
//   A: [M][K] row-major, W: [N][K] row-major (torch Linear weight), bias: [N]
//   SPLIT==1: C stored as [B][H][S][DK]   (row = b*SEQ+s, col = h*DK+dk)
//   SPLIT==0: C stored as [M][N]
// 64x64 tile, 256 threads, 4x4 microtile, KT=16.
// ---------------------------------------------------------------------------
template <int SPLIT>
__global__ __launch_bounds__(256) void gemm_bias_kernel(
    const float* __restrict__ A, const float* __restrict__ W,
    const float* __restrict__ bias, float* __restrict__ C,
    int M, int N, int K)
{
    constexpr int TILE = 64, KT = 16;
    __shared__ float As[KT][TILE + 4];   // [k][m], pad 4 keeps float4 alignment
    __shared__ float Ws[KT][TILE + 4];   // [k][n]

    const int tid = threadIdx.x;
    const int tx = tid & 15;   // n quad index
    const int ty = tid >> 4;   // m quad index
    const int bm = blockIdx.x * TILE;
    const int bn = blockIdx.y * TILE;
    const int lrow = tid >> 2;          // 0..63
    const int lk4  = (tid & 3) << 2;    // 0,4,8,12

    float acc[4][4] = {{0.f}};

    for (int k0 = 0; k0 < K; k0 += KT) {
        const float4 a4 = *(const float4*)&A[(size_t)(bm + lrow) * K + k0 + lk4];
        const float4 w4 = *(const float4*)&W[(size_t)(bn + lrow) * K + k0 + lk4];
        __syncthreads();
        As[lk4 + 0][lrow] = a4.x; As[lk4 + 1][lrow] = a4.y;
        As[lk4 + 2][lrow] = a4.z; As[lk4 + 3][lrow] = a4.w;
        Ws[lk4 + 0][lrow] = w4.x; Ws[lk4 + 1][lrow] = w4.y;
        Ws[lk4 + 2][lrow] = w4.z; Ws[lk4 + 3][lrow] = w4.w;
        __syncthreads();
        #pragma unroll
        for (int kk = 0; kk < KT; ++kk) {
            const float4 av = *(const float4*)&As[kk][ty << 2];
            const float4 wv = *(const float4*)&Ws[kk][tx << 2];
            acc[0][0] += av.x * wv.x; acc[0][1] += av.x * wv.y;
            acc[0][2] += av.x * wv.z; acc[0][3] += av.x * wv.w;
            acc[1][0] += av.y * wv.x; acc[1][1] += av.y * wv.y;
            acc[1][2] += av.y * wv.z; acc[1][3] += av.y * wv.w;
            acc[2][0] += av.z * wv.x; acc[2][1] += av.z * wv.y;
            acc[2][2] += av.z * wv.z; acc[2][3] += av.z * wv.w;
            acc[3][0] += av.w * wv.x; acc[3][1] += av.w * wv.y;
            acc[3][2] += av.w * wv.z; acc[3][3] += av.w * wv.w;
        }
    }

    const float4 bb = *(const float4*)&bias[bn + (tx << 2)];
    #pragma unroll
    for (int i = 0; i < 4; ++i) {
        const int row = bm + (ty << 2) + i;
        float4 o;
        o.x = acc[i][0] + bb.x; o.y = acc[i][1] + bb.y;
        o.z = acc[i][2] + bb.z; o.w = acc[i][3] + bb.w;
        if (SPLIT) {
            const int b = row >> 11;            // row / SEQ
            const int s = row & (SEQ - 1);
            const int h = bn >> 6;              // whole 64-wide tile = one head
            float* dst = C + ((size_t)((b * NUM_HEADS + h) * SEQ + s)) * DK + (tx << 2);
            *(float4*)dst = o;
        } else {
            *(float4*)&C[(size_t)row * N + bn + (tx << 2)] = o;
        }
    }
}

// ---------------------------------------------------------------------------
// Flash attention: one wave (64 threads) per (b, h, 64-row q-tile).
// Each lane owns one q row: Q row + ctx accumulator in registers.
// K/V 64x64 tiles staged in LDS; all lanes read the same K/V row (broadcast).
// Online softmax with rare-rescale branch; mask is wave-uniform -> ballot skip.
// ctx written directly in concat layout (B, S, D_MODEL).
// ---------------------------------------------------------------------------
__global__ __launch_bounds__(64) void attn_kernel(
    const float* __restrict__ Q, const float* __restrict__ K,
    const float* __restrict__ V, const int* __restrict__ mask,
    float* __restrict__ CTX)
{
    const int qt  = blockIdx.x;  // 0..31
    const int h   = blockIdx.y;  // 0..15
    const int b   = blockIdx.z;  // 0..1
    const int tid = threadIdx.x; // 0..63
    const int bh  = b * NUM_HEADS + h;

    const float* Qb = Q + (size_t)bh * SEQ * DK;
    const float* Kb = K + (size_t)bh * SEQ * DK;
    const float* Vb = V + (size_t)bh * SEQ * DK;
    const int*   mb = mask + b * SEQ;

    __shared__ float Ks[64][68];
    __shared__ float Vs[64][68];

    float q[DK], ctx[DK];
    const int q0 = qt * 64;
    #pragma unroll
    for (int d4 = 0; d4 < 16; ++d4) {
        const float4 t = *(const float4*)&Qb[(size_t)(q0 + tid) * DK + 4 * d4];
        q[4 * d4 + 0] = t.x; q[4 * d4 + 1] = t.y;
        q[4 * d4 + 2] = t.z; q[4 * d4 + 3] = t.w;
        ctx[4 * d4 + 0] = 0.f; ctx[4 * d4 + 1] = 0.f;
        ctx[4 * d4 + 2] = 0.f; ctx[4 * d4 + 3] = 0.f;
    }
    float m = -INFINITY, l = 0.f;

    for (int k0 = 0; k0 < SEQ; k0 += 64) {
        const unsigned long long mbits = __ballot(mb[k0 + tid] != 0);
        const float* Kt = Kb + (size_t)k0 * DK;
        const float* Vt = Vb + (size_t)k0 * DK;
        __syncthreads();
        #pragma unroll
        for (int i = 0; i < 16; ++i) {
            const int f4 = i * 64 + tid;           // 0..1023 float4s (contiguous tile)
            const int r = f4 >> 4, c = (f4 & 15) << 2;
            *(float4*)&Ks[r][c] = *(const float4*)&Kt[4 * f4];
            *(float4*)&Vs[r][c] = *(const float4*)&Vt[4 * f4];
        }
        __syncthreads();
        if (mbits == 0ULL) continue;               // uniform: whole tile masked

        for (int k = 0; k < 64; ++k) {
            if (!((mbits >> k) & 1ULL)) continue;  // uniform branch
            // 4 partial sums: shorten the dependent FMA chain
            float s0 = 0.f, s1 = 0.f, s2 = 0.f, s3 = 0.f;
            #pragma unroll
            for (int d4 = 0; d4 < 16; ++d4) {
                const float4 kv = *(const float4*)&Ks[k][4 * d4];
                s0 += q[4 * d4 + 0] * kv.x;
                s1 += q[4 * d4 + 1] * kv.y;
                s2 += q[4 * d4 + 2] * kv.z;
                s3 += q[4 * d4 + 3] * kv.w;
            }
            float s = ((s0 + s1) + (s2 + s3)) * 0.125f;  // 1/sqrt(64)
            float p;
            if (s > m) {                    // per-lane, rare after warm-up
                const float scale = __expf(m - s);  // m=-inf -> 0 (first hit)
                l *= scale;
                #pragma unroll
                for (int d = 0; d < DK; ++d) ctx[d] *= scale;
                m = s;
                p = 1.f;
            } else {
                p = __expf(s - m);
            }
            l += p;
            #pragma unroll
            for (int d4 = 0; d4 < 16; ++d4) {
                const float4 vv = *(const float4*)&Vs[k][4 * d4];
                ctx[4 * d4 + 0] += p * vv.x;
                ctx[4 * d4 + 1] += p * vv.y;
                ctx[4 * d4 + 2] += p * vv.z;
                ctx[4 * d4 + 3] += p * vv.w;
            }
        }
    }

    const float inv = (l > 0.f) ? (1.f / l) : 0.f;  // l==0: fully masked -> 0
    float* dst = CTX + ((size_t)(b * SEQ + q0 + tid)) * D_MODEL + h * DK;
    #pragma unroll
    for (int d4 = 0; d4 < 16; ++d4) {
        float4 o;
        o.x = ctx[4 * d4 + 0] * inv; o.y = ctx[4 * d4 + 1] * inv;
        o.z = ctx[4 * d4 + 2] * inv; o.w = ctx[4 * d4 + 3] * inv;
        *(float4*)&dst[4 * d4] = o;
    }
}

// ---------------------------------------------------------------------------
extern "C" void kernel_launch(void* const* d_in, const int* in_sizes, int n_in,
                              void* d_out, int out_size, void* d_ws, size_t ws_size,
                              hipStream_t stream)
{
    const float* query = (const float*)d_in[0];
    const float* key_  = (const float*)d_in[1];
    const float* value = (const float*)d_in[2];
    const int*   mask  = (const int*)d_in[3];
    const float* Wq = (const float*)d_in[4];
    const float* bq = (const float*)d_in[5];
    const float* Wk = (const float*)d_in[6];
    const float* bk = (const float*)d_in[7];
    const float* Wv = (const float*)d_in[8];
    const float* bv = (const float*)d_in[9];
    const float* Wo = (const float*)d_in[10];
    const float* bo = (const float*)d_in[11];
    float* out = (float*)d_out;

    const int M = BATCH * SEQ;   // 4096
    const int N = D_MODEL;       // 1024
    const int K = D_MODEL;       // 1024

    const size_t PER = (size_t)BATCH * SEQ * D_MODEL;  // 4,194,304 floats
    float* ws   = (float*)d_ws;
    float* q_ws = ws;
    float* k_ws = ws + PER;
    float* v_ws = ws + 2 * PER;
    float* c_ws = ws + 3 * PER;

    dim3 ggrid(M / 64, N / 64);
    dim3 gblk(256);
    gemm_bias_kernel<1><<<ggrid, gblk, 0, stream>>>(query, Wq, bq, q_ws, M, N, K);
    gemm_bias_kernel<1><<<ggrid, gblk, 0, stream>>>(key_,  Wk, bk, k_ws, M, N, K);
    gemm_bias_kernel<1><<<ggrid, gblk, 0, stream>>>(value, Wv, bv, v_ws, M, N, K);

    dim3 agrid(SEQ / 64, NUM_HEADS, BATCH);
    attn_kernel<<<agrid, dim3(64), 0, stream>>>(q_ws, k_ws, v_ws, mask, c_ws);

    gemm_bias_kernel<0><<<ggrid, gblk, 0, stream>>>(c_ws, Wo, bo, out, M, N, K);
}

// Round 3
// 955.955 us; speedup vs baseline: 1.4526x; 1.4526x over previous
//
#include <hip/hip_runtime.h>
#include <math.h>

#define D_MODEL 1024
#define NUM_HEADS 16
#define DK 64
#define BATCH 2
#define SEQ 2048

// ---------------------------------------------------------------------------
// GEMM: C = A @ W^T + bias   (unchanged)
//   A: [M][K] row-major, W: [N][K] row-major, bias: [N]
//   SPLIT==1: C stored as [B][H][S][DK]; SPLIT==0: C stored as [M][N]
// ---------------------------------------------------------------------------
template <int SPLIT>
__global__ __launch_bounds__(256) void gemm_bias_kernel(
    const float* __restrict__ A, const float* __restrict__ W,
    const float* __restrict__ bias, float* __restrict__ C,
    int M, int N, int K)
{
    constexpr int TILE = 64, KT = 16;
    __shared__ float As[KT][TILE + 4];
    __shared__ float Ws[KT][TILE + 4];

    const int tid = threadIdx.x;
    const int tx = tid & 15;
    const int ty = tid >> 4;
    const int bm = blockIdx.x * TILE;
    const int bn = blockIdx.y * TILE;
    const int lrow = tid >> 2;
    const int lk4  = (tid & 3) << 2;

    float acc[4][4] = {{0.f}};

    for (int k0 = 0; k0 < K; k0 += KT) {
        const float4 a4 = *(const float4*)&A[(size_t)(bm + lrow) * K + k0 + lk4];
        const float4 w4 = *(const float4*)&W[(size_t)(bn + lrow) * K + k0 + lk4];
        __syncthreads();
        As[lk4 + 0][lrow] = a4.x; As[lk4 + 1][lrow] = a4.y;
        As[lk4 + 2][lrow] = a4.z; As[lk4 + 3][lrow] = a4.w;
        Ws[lk4 + 0][lrow] = w4.x; Ws[lk4 + 1][lrow] = w4.y;
        Ws[lk4 + 2][lrow] = w4.z; Ws[lk4 + 3][lrow] = w4.w;
        __syncthreads();
        #pragma unroll
        for (int kk = 0; kk < KT; ++kk) {
            const float4 av = *(const float4*)&As[kk][ty << 2];
            const float4 wv = *(const float4*)&Ws[kk][tx << 2];
            acc[0][0] += av.x * wv.x; acc[0][1] += av.x * wv.y;
            acc[0][2] += av.x * wv.z; acc[0][3] += av.x * wv.w;
            acc[1][0] += av.y * wv.x; acc[1][1] += av.y * wv.y;
            acc[1][2] += av.y * wv.z; acc[1][3] += av.y * wv.w;
            acc[2][0] += av.z * wv.x; acc[2][1] += av.z * wv.y;
            acc[2][2] += av.z * wv.z; acc[2][3] += av.z * wv.w;
            acc[3][0] += av.w * wv.x; acc[3][1] += av.w * wv.y;
            acc[3][2] += av.w * wv.z; acc[3][3] += av.w * wv.w;
        }
    }

    const float4 bb = *(const float4*)&bias[bn + (tx << 2)];
    #pragma unroll
    for (int i = 0; i < 4; ++i) {
        const int row = bm + (ty << 2) + i;
        float4 o;
        o.x = acc[i][0] + bb.x; o.y = acc[i][1] + bb.y;
        o.z = acc[i][2] + bb.z; o.w = acc[i][3] + bb.w;
        if (SPLIT) {
            const int b = row >> 11;
            const int s = row & (SEQ - 1);
            const int h = bn >> 6;
            float* dst = C + ((size_t)((b * NUM_HEADS + h) * SEQ + s)) * DK + (tx << 2);
            *(float4*)dst = o;
        } else {
            *(float4*)&C[(size_t)row * N + bn + (tx << 2)] = o;
        }
    }
}

// ---------------------------------------------------------------------------
// Flash attention, restructured:
//  - 256 threads (4 waves), each wave owns a 64-row q-tile; block = 256 q rows
//  - staging of 64-key K/V tiles shared by all 4 waves
//  - NSPLIT-way split over the key range; NSPLIT==2 writes partial (ctx,m,l),
//    NSPLIT==1 writes normalized ctx directly in concat layout
//  - scores computed 16 at a time into registers (ILP), one chunk-max, at
//    most one rescale per chunk (instead of a branchy rescale per key)
//  - mask is wave-uniform -> ballot bit-skip (~50% of keys free)
// ---------------------------------------------------------------------------
template <int NSPLIT>
__global__ __launch_bounds__(256, 2) void attn_split_kernel(
    const float* __restrict__ Q, const float* __restrict__ K,
    const float* __restrict__ V, const int* __restrict__ mask,
    float* __restrict__ OUT,      // NSPLIT==1: ctx (B,S,D_MODEL); ==2: pctx
    float* __restrict__ PM, float* __restrict__ PL)
{
    const int sp = (NSPLIT == 2) ? (blockIdx.x & 1) : 0;
    const int qb = (NSPLIT == 2) ? (blockIdx.x >> 1) : blockIdx.x;
    const int h  = blockIdx.y;
    const int b  = blockIdx.z;
    const int wave = threadIdx.x >> 6;
    const int lane = threadIdx.x & 63;
    const int tid  = threadIdx.x;
    const int bh   = b * NUM_HEADS + h;

    const float* Qb = Q + (size_t)bh * SEQ * DK;
    const float* Kb = K + (size_t)bh * SEQ * DK;
    const float* Vb = V + (size_t)bh * SEQ * DK;
    const int*   mb = mask + b * SEQ;

    __shared__ float Ks[64][68];
    __shared__ float Vs[64][68];

    const int row = qb * 256 + wave * 64 + lane;

    float q[DK], ctx[DK];
    #pragma unroll
    for (int d4 = 0; d4 < 16; ++d4) {
        const float4 t = *(const float4*)&Qb[(size_t)row * DK + 4 * d4];
        q[4 * d4 + 0] = t.x; q[4 * d4 + 1] = t.y;
        q[4 * d4 + 2] = t.z; q[4 * d4 + 3] = t.w;
        ctx[4 * d4 + 0] = 0.f; ctx[4 * d4 + 1] = 0.f;
        ctx[4 * d4 + 2] = 0.f; ctx[4 * d4 + 3] = 0.f;
    }
    float m = -INFINITY, l = 0.f;

    const int koff = sp * (SEQ / NSPLIT);
    constexpr int NT = (SEQ / NSPLIT) / 64;

    for (int t = 0; t < NT; ++t) {
        const int k0 = koff + t * 64;
        const float* Kt = Kb + (size_t)k0 * DK;
        const float* Vt = Vb + (size_t)k0 * DK;
        __syncthreads();
        #pragma unroll
        for (int i = 0; i < 4; ++i) {
            const int f4 = i * 256 + tid;          // 0..1023
            const int r = f4 >> 4, c = (f4 & 15) << 2;
            *(float4*)&Ks[r][c] = *(const float4*)&Kt[4 * f4];
            *(float4*)&Vs[r][c] = *(const float4*)&Vt[4 * f4];
        }
        __syncthreads();
        const unsigned long long mbits = __ballot(mb[k0 + lane] != 0);
        if (mbits == 0ULL) continue;

        for (int c0 = 0; c0 < 64; c0 += 16) {
            const unsigned bits = (unsigned)((mbits >> c0) & 0xFFFFULL);
            if (!bits) continue;

            float sc[16];
            #pragma unroll
            for (int j = 0; j < 16; ++j) {
                if (!((bits >> j) & 1u)) { sc[j] = -INFINITY; continue; }
                float a0 = 0.f, a1 = 0.f, a2 = 0.f, a3 = 0.f;
                #pragma unroll
                for (int d4 = 0; d4 < 16; ++d4) {
                    const float4 kv = *(const float4*)&Ks[c0 + j][4 * d4];
                    a0 += q[4 * d4 + 0] * kv.x;
                    a1 += q[4 * d4 + 1] * kv.y;
                    a2 += q[4 * d4 + 2] * kv.z;
                    a3 += q[4 * d4 + 3] * kv.w;
                }
                sc[j] = ((a0 + a1) + (a2 + a3)) * 0.125f;   // 1/sqrt(64)
            }

            float cmax = sc[0];
            #pragma unroll
            for (int j = 1; j < 16; ++j) cmax = fmaxf(cmax, sc[j]);

            if (cmax > m) {                       // at most once per chunk
                const float scale = __expf(m - cmax);   // m=-inf -> 0
                l *= scale;
                #pragma unroll
                for (int d = 0; d < DK; ++d) ctx[d] *= scale;
                m = cmax;
            }

            #pragma unroll
            for (int j = 0; j < 16; ++j) {
                if (!((bits >> j) & 1u)) continue;
                const float p = __expf(sc[j] - m);
                l += p;
                #pragma unroll
                for (int d4 = 0; d4 < 16; ++d4) {
                    const float4 vv = *(const float4*)&Vs[c0 + j][4 * d4];
                    ctx[4 * d4 + 0] += p * vv.x;
                    ctx[4 * d4 + 1] += p * vv.y;
                    ctx[4 * d4 + 2] += p * vv.z;
                    ctx[4 * d4 + 3] += p * vv.w;
                }
            }
        }
    }

    if (NSPLIT == 1) {
        const float inv = (l > 0.f) ? (1.f / l) : 0.f;
        float* dst = OUT + ((size_t)(b * SEQ + row)) * D_MODEL + h * DK;
        #pragma unroll
        for (int d4 = 0; d4 < 16; ++d4) {
            float4 o;
            o.x = ctx[4 * d4 + 0] * inv; o.y = ctx[4 * d4 + 1] * inv;
            o.z = ctx[4 * d4 + 2] * inv; o.w = ctx[4 * d4 + 3] * inv;
            *(float4*)&dst[4 * d4] = o;
        }
    } else {
        const int rg = bh * SEQ + row;                       // 0..65535
        float* pc = OUT + ((size_t)sp * (BATCH * NUM_HEADS * SEQ) + rg) * DK;
        #pragma unroll
        for (int d4 = 0; d4 < 16; ++d4) {
            float4 o;
            o.x = ctx[4 * d4 + 0]; o.y = ctx[4 * d4 + 1];
            o.z = ctx[4 * d4 + 2]; o.w = ctx[4 * d4 + 3];
            *(float4*)&pc[4 * d4] = o;
        }
        PM[sp * (BATCH * NUM_HEADS * SEQ) + rg] = m;
        PL[sp * (BATCH * NUM_HEADS * SEQ) + rg] = l;
    }
}

// Merge 2 split partials -> normalized ctx in concat layout (B, S, D_MODEL).
__global__ __launch_bounds__(256) void attn_combine_kernel(
    const float* __restrict__ PCTX, const float* __restrict__ PM,
    const float* __restrict__ PL, float* __restrict__ CTX)
{
    const int gid = blockIdx.x * 256 + threadIdx.x;   // 0 .. 2*16*2048*16-1
    const int d4 = gid & 15;
    const int rg = gid >> 4;                          // bh*2048 + s
    const int bh = rg >> 11;
    const int s  = rg & (SEQ - 1);
    const int b  = bh >> 4;
    const int h  = bh & 15;
    constexpr int STRIDE = BATCH * NUM_HEADS * SEQ;   // 65536

    const float mA = PM[rg],          mB = PM[STRIDE + rg];
    const float lA = PL[rg],          lB = PL[STRIDE + rg];
    const float M = fmaxf(mA, mB);

    float4 o = make_float4(0.f, 0.f, 0.f, 0.f);
    if (M > -INFINITY) {
        const float eA = __expf(mA - M);
        const float eB = __expf(mB - M);
        const float den = eA * lA + eB * lB;
        const float inv = (den > 0.f) ? (1.f / den) : 0.f;
        const float4 cA = *(const float4*)&PCTX[(size_t)rg * DK + 4 * d4];
        const float4 cB = *(const float4*)&PCTX[(size_t)(STRIDE + rg) * DK + 4 * d4];
        o.x = (eA * cA.x + eB * cB.x) * inv;
        o.y = (eA * cA.y + eB * cB.y) * inv;
        o.z = (eA * cA.z + eB * cB.z) * inv;
        o.w = (eA * cA.w + eB * cB.w) * inv;
    }
    *(float4*)&CTX[((size_t)(b * SEQ + s)) * D_MODEL + h * DK + 4 * d4] = o;
}

// ---------------------------------------------------------------------------
extern "C" void kernel_launch(void* const* d_in, const int* in_sizes, int n_in,
                              void* d_out, int out_size, void* d_ws, size_t ws_size,
                              hipStream_t stream)
{
    const float* query = (const float*)d_in[0];
    const float* key_  = (const float*)d_in[1];
    const float* value = (const float*)d_in[2];
    const int*   mask  = (const int*)d_in[3];
    const float* Wq = (const float*)d_in[4];
    const float* bq = (const float*)d_in[5];
    const float* Wk = (const float*)d_in[6];
    const float* bk = (const float*)d_in[7];
    const float* Wv = (const float*)d_in[8];
    const float* bv = (const float*)d_in[9];
    const float* Wo = (const float*)d_in[10];
    const float* bo = (const float*)d_in[11];
    float* out = (float*)d_out;

    const int M = BATCH * SEQ;   // 4096
    const int N = D_MODEL;       // 1024
    const int K = D_MODEL;       // 1024

    const size_t PER = (size_t)BATCH * SEQ * D_MODEL;     // 4,194,304 floats
    const size_t NROW = (size_t)BATCH * NUM_HEADS * SEQ;  // 65,536

    float* ws   = (float*)d_ws;
    float* q_ws = ws;
    float* k_ws = ws + PER;
    float* v_ws = ws + 2 * PER;

    dim3 ggrid(M / 64, N / 64);
    dim3 gblk(256);
    gemm_bias_kernel<1><<<ggrid, gblk, 0, stream>>>(query, Wq, bq, q_ws, M, N, K);
    gemm_bias_kernel<1><<<ggrid, gblk, 0, stream>>>(key_,  Wk, bk, k_ws, M, N, K);
    gemm_bias_kernel<1><<<ggrid, gblk, 0, stream>>>(value, Wv, bv, v_ws, M, N, K);

    const size_t split2_floats = 5 * PER + 4 * NROW;      // ~85 MB
    float* c_ws;

    if (ws_size >= split2_floats * sizeof(float)) {
        float* pctx = ws + 3 * PER;          // 2 * PER floats
        float* pm   = ws + 5 * PER;          // 2 * NROW
        float* pl   = pm + 2 * NROW;         // 2 * NROW
        c_ws = q_ws;                         // q dead after attn_split

        dim3 agrid((SEQ / 256) * 2, NUM_HEADS, BATCH);    // 16,16,2 = 512 blocks
        attn_split_kernel<2><<<agrid, dim3(256), 0, stream>>>(
            q_ws, k_ws, v_ws, mask, pctx, pm, pl);

        const int total = (int)(NROW * 16);               // d4 groups
        attn_combine_kernel<<<total / 256, dim3(256), 0, stream>>>(
            pctx, pm, pl, c_ws);
    } else {
        c_ws = ws + 3 * PER;
        dim3 agrid(SEQ / 256, NUM_HEADS, BATCH);          // 8,16,2 = 256 blocks
        attn_split_kernel<1><<<agrid, dim3(256), 0, stream>>>(
            q_ws, k_ws, v_ws, mask, c_ws, nullptr, nullptr);
    }

    gemm_bias_kernel<0><<<ggrid, gblk, 0, stream>>>(c_ws, Wo, bo, out, M, N, K);
}